// Round 1
// baseline (1964.838 us; speedup 1.0000x reference)
//
#include <hip/hip_runtime.h>
#include <math.h>

#define Bdim 2
#define Sdim 2048
#define Ddim 1024
#define Hnum 16
#define HDdim 64

// ---------------------------------------------------------------------------
// Fused QKV projection GEMM: C = x @ {Wq|Wk|Wv} + bias
// M=4096 (B*S), N=3072 (q|k|v), K=1024. 128x128 tile, 8x8 microtile.
// Output written in [B, H, S, HD] layout for the attention kernel.
// ---------------------------------------------------------------------------
__global__ __launch_bounds__(256) void qkv_gemm_kernel(
    const float* __restrict__ x,
    const float* __restrict__ Wq, const float* __restrict__ Wk, const float* __restrict__ Wv,
    const float* __restrict__ bq, const float* __restrict__ bk, const float* __restrict__ bv,
    float* __restrict__ qo, float* __restrict__ ko, float* __restrict__ vo)
{
    __shared__ float As[128][20];   // [m][k], pad to 20 (80B row, 16B aligned)
    __shared__ float Bs[16][132];   // [k][n], pad to 132 (528B row, 16B aligned)

    const int t  = threadIdx.x;
    const int tx = t & 15;
    const int ty = t >> 4;
    const int n0 = blockIdx.x * 128;
    const int m0 = blockIdx.y * 128;
    const int wsel = n0 >> 10;           // 0=q 1=k 2=v (128 | 1024 so no crossing)
    const int c0   = n0 & 1023;
    const float* __restrict__ W    = (wsel == 0) ? Wq : (wsel == 1 ? Wk : Wv);
    const float* __restrict__ bias = (wsel == 0) ? bq : (wsel == 1 ? bk : bv);
    float* __restrict__ outp       = (wsel == 0) ? qo : (wsel == 1 ? ko : vo);

    const int ar0 = t >> 2;          // 0..63 (A row, +64 for second)
    const int ac  = (t & 3) * 4;     // 0..12 (A col float4)
    const int br0 = t >> 5;          // 0..7  (B row, +8 for second)
    const int bc  = (t & 31) * 4;    // 0..124

    float acc[8][8];
#pragma unroll
    for (int i = 0; i < 8; ++i)
#pragma unroll
        for (int j = 0; j < 8; ++j) acc[i][j] = 0.f;

    for (int kt = 0; kt < 64; ++kt) {
        const int k0 = kt * 16;
        // global prefetch into registers (before barrier: hides latency)
        float4 av0 = *(const float4*)(x + (size_t)(m0 + ar0) * Ddim + k0 + ac);
        float4 av1 = *(const float4*)(x + (size_t)(m0 + ar0 + 64) * Ddim + k0 + ac);
        float4 bw0 = *(const float4*)(W + (size_t)(k0 + br0) * Ddim + c0 + bc);
        float4 bw1 = *(const float4*)(W + (size_t)(k0 + br0 + 8) * Ddim + c0 + bc);
        __syncthreads();                 // previous tile compute done
        *(float4*)&As[ar0][ac]        = av0;
        *(float4*)&As[ar0 + 64][ac]   = av1;
        *(float4*)&Bs[br0][bc]        = bw0;
        *(float4*)&Bs[br0 + 8][bc]    = bw1;
        __syncthreads();
#pragma unroll
        for (int k4 = 0; k4 < 4; ++k4) {
            float4 a4[8];
#pragma unroll
            for (int i = 0; i < 8; ++i)
                a4[i] = *(const float4*)&As[i * 16 + ty][k4 * 4];
#pragma unroll
            for (int kk = 0; kk < 4; ++kk) {
                float4 b0 = *(const float4*)&Bs[k4 * 4 + kk][tx * 8];
                float4 b1 = *(const float4*)&Bs[k4 * 4 + kk][tx * 8 + 4];
#pragma unroll
                for (int i = 0; i < 8; ++i) {
                    float av = ((const float*)&a4[i])[kk];
                    acc[i][0] += av * b0.x; acc[i][1] += av * b0.y;
                    acc[i][2] += av * b0.z; acc[i][3] += av * b0.w;
                    acc[i][4] += av * b1.x; acc[i][5] += av * b1.y;
                    acc[i][6] += av * b1.z; acc[i][7] += av * b1.w;
                }
            }
        }
    }

    float bvv[8];
#pragma unroll
    for (int j = 0; j < 8; ++j) bvv[j] = bias[c0 + tx * 8 + j];

    const int colW = c0 + tx * 8;
    const int h  = colW >> 6;
    const int hd = colW & 63;            // 8 | 64 so a thread never crosses heads
#pragma unroll
    for (int i = 0; i < 8; ++i) {
        int m    = m0 + i * 16 + ty;
        int bidx = m >> 11;              // / 2048
        int s    = m & 2047;
        float* dst = outp + ((size_t)(bidx * Hnum + h) * Sdim + s) * HDdim + hd;
        *(float4*)dst       = make_float4(acc[i][0] + bvv[0], acc[i][1] + bvv[1],
                                          acc[i][2] + bvv[2], acc[i][3] + bvv[3]);
        *(float4*)(dst + 4) = make_float4(acc[i][4] + bvv[4], acc[i][5] + bvv[5],
                                          acc[i][6] + bvv[6], acc[i][7] + bvv[7]);
    }
}

// ---------------------------------------------------------------------------
// Flash attention, fp32, online softmax.
// Block = 256 threads handles (b, h, 64-query tile). K-tiles of 64.
// Scores: thread(ty,tx) owns q rows {i*16+ty}, k cols {j*16+tx} (4x4).
// Ctx:    thread(ty,tx) owns q rows {i*16+ty}, hd cols {tx*4+jc} (4x4).
// ---------------------------------------------------------------------------
__global__ __launch_bounds__(256) void attn_kernel(
    const float* __restrict__ q, const float* __restrict__ k,
    const float* __restrict__ v, const int* __restrict__ mask,
    const float* __restrict__ cmw, float* __restrict__ ctx)
{
    __shared__ float Qs[64][68];
    __shared__ float Ks[64][68];
    __shared__ float Vs[64][68];
    __shared__ float Ps[64][68];
    __shared__ float sbias;

    const int t  = threadIdx.x;
    const int tx = t & 15;
    const int ty = t >> 4;
    const int qt = blockIdx.x;
    const int bh = blockIdx.y;
    const int b  = bh >> 4;
    const int h  = bh & 15;

    if (t == 0) {
        float s = 0.f;
        for (int i = 0; i < 9; ++i) s += cmw[i];
        sbias = s * (1.0f / 9.0f);
    }

    const float* qbase = q + ((size_t)bh * Sdim + qt * 64) * HDdim;
#pragma unroll
    for (int it = 0; it < 4; ++it) {
        int idx = t + it * 256;
        int row = idx >> 4;
        int c4  = (idx & 15) * 4;
        *(float4*)&Qs[row][c4] = *(const float4*)(qbase + row * 64 + c4);
    }
    __syncthreads();
    const float mbias = sbias;

    float m_i[4], l_i[4], acc[4][4];
#pragma unroll
    for (int i = 0; i < 4; ++i) {
        m_i[i] = -INFINITY;
        l_i[i] = 0.f;
#pragma unroll
        for (int jc = 0; jc < 4; ++jc) acc[i][jc] = 0.f;
    }

    const int qg0 = qt * 64;
    for (int kt = 0; kt < 32; ++kt) {
        const float* kbase = k + ((size_t)bh * Sdim + kt * 64) * HDdim;
        const float* vbase = v + ((size_t)bh * Sdim + kt * 64) * HDdim;
        float4 kr[4], vr[4];
#pragma unroll
        for (int it = 0; it < 4; ++it) {
            int idx = t + it * 256;
            int row = idx >> 4;
            int c4  = (idx & 15) * 4;
            kr[it] = *(const float4*)(kbase + row * 64 + c4);
            vr[it] = *(const float4*)(vbase + row * 64 + c4);
        }
        __syncthreads();   // previous PV done (Ks/Vs/Ps free to overwrite)
#pragma unroll
        for (int it = 0; it < 4; ++it) {
            int idx = t + it * 256;
            int row = idx >> 4;
            int c4  = (idx & 15) * 4;
            *(float4*)&Ks[row][c4] = kr[it];
            *(float4*)&Vs[row][c4] = vr[it];
        }
        __syncthreads();

        // ---- scores: S = Q K^T ----
        float sc[4][4];
#pragma unroll
        for (int i = 0; i < 4; ++i)
#pragma unroll
            for (int j = 0; j < 4; ++j) sc[i][j] = 0.f;
#pragma unroll
        for (int k4 = 0; k4 < 16; ++k4) {
            float4 a4[4], b4[4];
#pragma unroll
            for (int i = 0; i < 4; ++i) a4[i] = *(const float4*)&Qs[i * 16 + ty][k4 * 4];
#pragma unroll
            for (int j = 0; j < 4; ++j) b4[j] = *(const float4*)&Ks[j * 16 + tx][k4 * 4];
#pragma unroll
            for (int i = 0; i < 4; ++i)
#pragma unroll
                for (int j = 0; j < 4; ++j)
                    sc[i][j] += a4[i].x * b4[j].x + a4[i].y * b4[j].y +
                                a4[i].z * b4[j].z + a4[i].w * b4[j].w;
        }

        // ---- mask + bias + online softmax ----
#pragma unroll
        for (int i = 0; i < 4; ++i) {
            int qg = qg0 + i * 16 + ty;
            const int* mrow = mask + ((size_t)b * Sdim + qg) * Sdim + kt * 64;
            float srow[4];
#pragma unroll
            for (int j = 0; j < 4; ++j) {
                float sv = sc[i][j] * 0.125f + mbias;     // 1/sqrt(64)=0.125
                int mv = mrow[j * 16 + tx];
                srow[j] = (mv == 0) ? -1e9f : sv;
            }
            float rmax = fmaxf(fmaxf(srow[0], srow[1]), fmaxf(srow[2], srow[3]));
#pragma unroll
            for (int off = 8; off >= 1; off >>= 1)
                rmax = fmaxf(rmax, __shfl_xor(rmax, off, 64));
            float mnew  = fmaxf(m_i[i], rmax);
            float alpha = __expf(m_i[i] - mnew);          // exp(-inf)=0 first tile
            float rsum  = 0.f;
#pragma unroll
            for (int j = 0; j < 4; ++j) {
                float p = __expf(srow[j] - mnew);
                Ps[i * 16 + ty][j * 16 + tx] = p;
                rsum += p;
            }
#pragma unroll
            for (int off = 8; off >= 1; off >>= 1)
                rsum += __shfl_xor(rsum, off, 64);
            l_i[i] = l_i[i] * alpha + rsum;
            m_i[i] = mnew;
#pragma unroll
            for (int jc = 0; jc < 4; ++jc) acc[i][jc] *= alpha;
        }
        __syncthreads();   // Ps visible to all

        // ---- PV: acc += P V ----
#pragma unroll
        for (int k4 = 0; k4 < 16; ++k4) {
            float4 pr[4], vv[4];
#pragma unroll
            for (int i = 0; i < 4; ++i)  pr[i]  = *(const float4*)&Ps[i * 16 + ty][k4 * 4];
#pragma unroll
            for (int kk = 0; kk < 4; ++kk) vv[kk] = *(const float4*)&Vs[k4 * 4 + kk][tx * 4];
#pragma unroll
            for (int i = 0; i < 4; ++i) {
                float4 p = pr[i];
                acc[i][0] += p.x * vv[0].x + p.y * vv[1].x + p.z * vv[2].x + p.w * vv[3].x;
                acc[i][1] += p.x * vv[0].y + p.y * vv[1].y + p.z * vv[2].y + p.w * vv[3].y;
                acc[i][2] += p.x * vv[0].z + p.y * vv[1].z + p.z * vv[2].z + p.w * vv[3].z;
                acc[i][3] += p.x * vv[0].w + p.y * vv[1].w + p.z * vv[2].w + p.w * vv[3].w;
            }
        }
    }

    // epilogue: ctx in [B, S, D] layout for output GEMM
#pragma unroll
    for (int i = 0; i < 4; ++i) {
        float inv = 1.0f / l_i[i];
        int sg = qg0 + i * 16 + ty;
        float* dst = ctx + ((size_t)(b * Sdim + sg)) * Ddim + h * 64 + tx * 4;
        *(float4*)dst = make_float4(acc[i][0] * inv, acc[i][1] * inv,
                                    acc[i][2] * inv, acc[i][3] * inv);
    }
}

// ---------------------------------------------------------------------------
// Output projection: out = ctx @ Wo + bo.  M=4096, N=1024, K=1024.
// ---------------------------------------------------------------------------
__global__ __launch_bounds__(256) void out_gemm_kernel(
    const float* __restrict__ A, const float* __restrict__ W,
    const float* __restrict__ bias, float* __restrict__ out)
{
    __shared__ float As[128][20];
    __shared__ float Bs[16][132];

    const int t  = threadIdx.x;
    const int tx = t & 15;
    const int ty = t >> 4;
    const int n0 = blockIdx.x * 128;
    const int m0 = blockIdx.y * 128;

    const int ar0 = t >> 2;
    const int ac  = (t & 3) * 4;
    const int br0 = t >> 5;
    const int bc  = (t & 31) * 4;

    float acc[8][8];
#pragma unroll
    for (int i = 0; i < 8; ++i)
#pragma unroll
        for (int j = 0; j < 8; ++j) acc[i][j] = 0.f;

    for (int kt = 0; kt < 64; ++kt) {
        const int k0 = kt * 16;
        float4 av0 = *(const float4*)(A + (size_t)(m0 + ar0) * Ddim + k0 + ac);
        float4 av1 = *(const float4*)(A + (size_t)(m0 + ar0 + 64) * Ddim + k0 + ac);
        float4 bw0 = *(const float4*)(W + (size_t)(k0 + br0) * Ddim + n0 + bc);
        float4 bw1 = *(const float4*)(W + (size_t)(k0 + br0 + 8) * Ddim + n0 + bc);
        __syncthreads();
        *(float4*)&As[ar0][ac]      = av0;
        *(float4*)&As[ar0 + 64][ac] = av1;
        *(float4*)&Bs[br0][bc]      = bw0;
        *(float4*)&Bs[br0 + 8][bc]  = bw1;
        __syncthreads();
#pragma unroll
        for (int k4 = 0; k4 < 4; ++k4) {
            float4 a4[8];
#pragma unroll
            for (int i = 0; i < 8; ++i)
                a4[i] = *(const float4*)&As[i * 16 + ty][k4 * 4];
#pragma unroll
            for (int kk = 0; kk < 4; ++kk) {
                float4 b0 = *(const float4*)&Bs[k4 * 4 + kk][tx * 8];
                float4 b1 = *(const float4*)&Bs[k4 * 4 + kk][tx * 8 + 4];
#pragma unroll
                for (int i = 0; i < 8; ++i) {
                    float av = ((const float*)&a4[i])[kk];
                    acc[i][0] += av * b0.x; acc[i][1] += av * b0.y;
                    acc[i][2] += av * b0.z; acc[i][3] += av * b0.w;
                    acc[i][4] += av * b1.x; acc[i][5] += av * b1.y;
                    acc[i][6] += av * b1.z; acc[i][7] += av * b1.w;
                }
            }
        }
    }

    float bvv[8];
#pragma unroll
    for (int j = 0; j < 8; ++j) bvv[j] = bias[n0 + tx * 8 + j];
#pragma unroll
    for (int i = 0; i < 8; ++i) {
        int m = m0 + i * 16 + ty;
        float* dst = out + (size_t)m * Ddim + n0 + tx * 8;
        *(float4*)dst       = make_float4(acc[i][0] + bvv[0], acc[i][1] + bvv[1],
                                          acc[i][2] + bvv[2], acc[i][3] + bvv[3]);
        *(float4*)(dst + 4) = make_float4(acc[i][4] + bvv[4], acc[i][5] + bvv[5],
                                          acc[i][6] + bvv[6], acc[i][7] + bvv[7]);
    }
}

// ---------------------------------------------------------------------------
extern "C" void kernel_launch(void* const* d_in, const int* in_sizes, int n_in,
                              void* d_out, int out_size, void* d_ws, size_t ws_size,
                              hipStream_t stream) {
    const float* x   = (const float*)d_in[0];
    const float* Wq  = (const float*)d_in[1];
    const float* bq  = (const float*)d_in[2];
    const float* Wk  = (const float*)d_in[3];
    const float* bk  = (const float*)d_in[4];
    const float* Wv  = (const float*)d_in[5];
    const float* bv  = (const float*)d_in[6];
    const float* Wo  = (const float*)d_in[7];
    const float* bo  = (const float*)d_in[8];
    const float* cmw = (const float*)d_in[9];
    const int*  mask = (const int*)d_in[10];
    // d_in[11] modality_info: unused by the reference
    float* out = (float*)d_out;

    float* ws    = (float*)d_ws;
    const size_t qkv_elems = (size_t)Bdim * Sdim * Ddim;  // 4,194,304
    float* qws   = ws;
    float* kws   = qws + qkv_elems;
    float* vws   = kws + qkv_elems;
    float* ctxws = vws + qkv_elems;

    qkv_gemm_kernel<<<dim3(24, 32), 256, 0, stream>>>(x, Wq, Wk, Wv, bq, bk, bv,
                                                      qws, kws, vws);
    attn_kernel<<<dim3(Sdim / 64, Bdim * Hnum), 256, 0, stream>>>(qws, kws, vws,
                                                                  mask, cmw, ctxws);
    out_gemm_kernel<<<dim3(8, 32), 256, 0, stream>>>(ctxws, Wo, bo, out);
}

// Round 2
// 697.117 us; speedup vs baseline: 2.8185x; 2.8185x over previous
//
#include <hip/hip_runtime.h>
#include <math.h>

#define Bdim 2
#define Sdim 2048
#define Ddim 1024
#define Hnum 16
#define HDdim 64

using short8  = __attribute__((ext_vector_type(8))) short;
using ushort8 = __attribute__((ext_vector_type(8))) unsigned short;
using floatx4 = __attribute__((ext_vector_type(4))) float;

__device__ __forceinline__ unsigned short f2bf(float f) {
    __bf16 b = (__bf16)f;
    return __builtin_bit_cast(unsigned short, b);
}

// ---------------------------------------------------------------------------
// Fused QKV projection GEMM (fp32 compute): C = x @ {Wq|Wk|Wv} + bias
// Outputs bf16 in [B*H, S, HD] layout; Q pre-scaled by 0.125*log2(e).
// ---------------------------------------------------------------------------
__global__ __launch_bounds__(256) void qkv_gemm_kernel(
    const float* __restrict__ x,
    const float* __restrict__ Wq, const float* __restrict__ Wk, const float* __restrict__ Wv,
    const float* __restrict__ bq, const float* __restrict__ bk, const float* __restrict__ bv,
    unsigned short* __restrict__ qo, unsigned short* __restrict__ ko, unsigned short* __restrict__ vo)
{
    __shared__ float As[128][20];
    __shared__ float Bs[16][132];

    const int t  = threadIdx.x;
    const int tx = t & 15;
    const int ty = t >> 4;
    const int n0 = blockIdx.x * 128;
    const int m0 = blockIdx.y * 128;
    const int wsel = n0 >> 10;
    const int c0   = n0 & 1023;
    const float* __restrict__ W    = (wsel == 0) ? Wq : (wsel == 1 ? Wk : Wv);
    const float* __restrict__ bias = (wsel == 0) ? bq : (wsel == 1 ? bk : bv);
    unsigned short* __restrict__ outp = (wsel == 0) ? qo : (wsel == 1 ? ko : vo);

    const int ar0 = t >> 2;
    const int ac  = (t & 3) * 4;
    const int br0 = t >> 5;
    const int bc  = (t & 31) * 4;

    float acc[8][8];
#pragma unroll
    for (int i = 0; i < 8; ++i)
#pragma unroll
        for (int j = 0; j < 8; ++j) acc[i][j] = 0.f;

    for (int kt = 0; kt < 64; ++kt) {
        const int k0 = kt * 16;
        float4 av0 = *(const float4*)(x + (size_t)(m0 + ar0) * Ddim + k0 + ac);
        float4 av1 = *(const float4*)(x + (size_t)(m0 + ar0 + 64) * Ddim + k0 + ac);
        float4 bw0 = *(const float4*)(W + (size_t)(k0 + br0) * Ddim + c0 + bc);
        float4 bw1 = *(const float4*)(W + (size_t)(k0 + br0 + 8) * Ddim + c0 + bc);
        __syncthreads();
        *(float4*)&As[ar0][ac]      = av0;
        *(float4*)&As[ar0 + 64][ac] = av1;
        *(float4*)&Bs[br0][bc]      = bw0;
        *(float4*)&Bs[br0 + 8][bc]  = bw1;
        __syncthreads();
#pragma unroll
        for (int k4 = 0; k4 < 4; ++k4) {
            float4 a4[8];
#pragma unroll
            for (int i = 0; i < 8; ++i)
                a4[i] = *(const float4*)&As[i * 16 + ty][k4 * 4];
#pragma unroll
            for (int kk = 0; kk < 4; ++kk) {
                float4 b0 = *(const float4*)&Bs[k4 * 4 + kk][tx * 8];
                float4 b1 = *(const float4*)&Bs[k4 * 4 + kk][tx * 8 + 4];
#pragma unroll
                for (int i = 0; i < 8; ++i) {
                    float av = ((const float*)&a4[i])[kk];
                    acc[i][0] += av * b0.x; acc[i][1] += av * b0.y;
                    acc[i][2] += av * b0.z; acc[i][3] += av * b0.w;
                    acc[i][4] += av * b1.x; acc[i][5] += av * b1.y;
                    acc[i][6] += av * b1.z; acc[i][7] += av * b1.w;
                }
            }
        }
    }

    float bvv[8];
#pragma unroll
    for (int j = 0; j < 8; ++j) bvv[j] = bias[c0 + tx * 8 + j];

    // Q pre-scale: 0.125 (1/sqrt(HD)) * log2(e), so attention can use exp2.
    const float qsc = (wsel == 0) ? 0.18033688011112042f : 1.0f;
    const int colW = c0 + tx * 8;
    const int h  = colW >> 6;
    const int hd = colW & 63;
#pragma unroll
    for (int i = 0; i < 8; ++i) {
        int m    = m0 + i * 16 + ty;
        int bidx = m >> 11;
        int s    = m & 2047;
        unsigned short* dst = outp + ((size_t)(bidx * Hnum + h) * Sdim + s) * HDdim + hd;
        ushort8 o;
#pragma unroll
        for (int j = 0; j < 8; ++j) o[j] = f2bf((acc[i][j] + bvv[j]) * qsc);
        *(ushort8*)dst = o;
    }
}

// ---------------------------------------------------------------------------
// Pack mask int32 [B,S,S] -> bitmask uint64 [B,S,S/64] via ballot.
// ---------------------------------------------------------------------------
__global__ __launch_bounds__(256) void pack_mask_kernel(
    const int* __restrict__ mask, unsigned long long* __restrict__ packed)
{
    const int t = threadIdx.x;
    const size_t widx = (size_t)blockIdx.x * 4 + (t >> 6);
    const int lane = t & 63;
    int mv = mask[widx * 64 + lane];
    unsigned long long bits = __ballot(mv != 0);
    if (lane == 0) packed[widx] = bits;
}

// ---------------------------------------------------------------------------
// Transpose V: bf16 [bh][s][hd] -> bf16 [bh][hd][s].
// ---------------------------------------------------------------------------
__global__ __launch_bounds__(256) void transpose_v_kernel(
    const unsigned short* __restrict__ v, unsigned short* __restrict__ vt)
{
    const int t  = threadIdx.x;
    const int s0 = blockIdx.x * 64;
    const int bh = blockIdx.y;
    const unsigned short* vp = v + (size_t)bh * Sdim * HDdim;
    unsigned short* vtp      = vt + (size_t)bh * HDdim * Sdim;
    const int c  = t & 63;
    const int rg = t >> 6;
#pragma unroll
    for (int half = 0; half < 2; ++half) {
        int r0 = (rg + half * 4) * 8;
        ushort8 o;
#pragma unroll
        for (int j = 0; j < 8; ++j) o[j] = vp[(size_t)(s0 + r0 + j) * HDdim + c];
        *(ushort8*)(vtp + (size_t)c * Sdim + s0 + r0) = o;
    }
}

// ---------------------------------------------------------------------------
// MFMA flash attention, bf16 inputs / fp32 accum, barrier-light.
// Block = 256 thr (4 waves). Each wave owns 32 q-rows independently.
// K/V frags straight from global (L2); P round-trips a private LDS slab.
// Scores computed in exp2 domain (Q pre-scaled); bias dropped (softmax-
// shift invariant); mask applied multiplicatively after exp (exact).
// ---------------------------------------------------------------------------
__global__ __launch_bounds__(256, 2) void attn_mfma_kernel(
    const unsigned short* __restrict__ q, const unsigned short* __restrict__ k,
    const unsigned short* __restrict__ vt, const unsigned int* __restrict__ pmask,
    float* __restrict__ ctx)
{
    __shared__ unsigned short Ps[4][32][72];   // per-wave private 32x64 (+8 pad)

    const int t    = threadIdx.x;
    const int w    = t >> 6;
    const int lane = t & 63;
    const int quad = lane >> 4;
    const int l15  = lane & 15;
    const int bh   = blockIdx.y;
    const int b    = bh >> 4;
    const int h    = bh & 15;
    const int qrow0 = blockIdx.x * 128 + w * 32;

    const unsigned short* qp = q  + (size_t)bh * Sdim * HDdim;
    const unsigned short* kp = k  + (size_t)bh * Sdim * HDdim;
    const unsigned short* vp = vt + (size_t)bh * HDdim * Sdim;

    // Q A-frags: qf[g][ks], row = qrow0+g*16+l15, hd = ks*32+quad*8..+8
    short8 qf[2][2];
#pragma unroll
    for (int g = 0; g < 2; ++g)
#pragma unroll
        for (int ks = 0; ks < 2; ++ks)
            qf[g][ks] = *(const short8*)(qp + (size_t)(qrow0 + g * 16 + l15) * HDdim + ks * 32 + quad * 8);

    floatx4 acc[2][4];
    float m_i[2][4], l_i[2][4];
#pragma unroll
    for (int g = 0; g < 2; ++g) {
#pragma unroll
        for (int hs = 0; hs < 4; ++hs) acc[g][hs] = (floatx4){0.f, 0.f, 0.f, 0.f};
#pragma unroll
        for (int r = 0; r < 4; ++r) { m_i[g][r] = -__builtin_inff(); l_i[g][r] = 0.f; }
    }

    for (int kt = 0; kt < 32; ++kt) {
        const int key0 = kt * 64;

        // K B-frags: kf[ks][sub], key = key0+sub*16+l15, hd = ks*32+quad*8..+8
        short8 kf[2][4];
#pragma unroll
        for (int ks = 0; ks < 2; ++ks)
#pragma unroll
            for (int sub = 0; sub < 4; ++sub)
                kf[ks][sub] = *(const short8*)(kp + (size_t)(key0 + sub * 16 + l15) * HDdim + ks * 32 + quad * 8);

        // V B-frags: vf[hs][ks], hd = hs*16+l15, key = key0+ks*32+quad*8..+8
        short8 vf[4][2];
#pragma unroll
        for (int hs = 0; hs < 4; ++hs)
#pragma unroll
            for (int ks = 0; ks < 2; ++ks)
                vf[hs][ks] = *(const short8*)(vp + (size_t)(hs * 16 + l15) * Sdim + key0 + ks * 32 + quad * 8);

        // mask bits: one uint64 per owned q-row
        unsigned int wlo[2][4], whi[2][4];
#pragma unroll
        for (int g = 0; g < 2; ++g)
#pragma unroll
            for (int r = 0; r < 4; ++r) {
                size_t mi = ((size_t)(b * Sdim + qrow0 + g * 16 + quad * 4 + r) * 32 + kt) * 2;
                wlo[g][r] = pmask[mi];
                whi[g][r] = pmask[mi + 1];
            }

        // ---- QK^T ----
        floatx4 sc[2][4];
#pragma unroll
        for (int g = 0; g < 2; ++g)
#pragma unroll
            for (int sub = 0; sub < 4; ++sub) sc[g][sub] = (floatx4){0.f, 0.f, 0.f, 0.f};
#pragma unroll
        for (int ks = 0; ks < 2; ++ks)
#pragma unroll
            for (int sub = 0; sub < 4; ++sub)
#pragma unroll
                for (int g = 0; g < 2; ++g)
                    sc[g][sub] = __builtin_amdgcn_mfma_f32_16x16x32_bf16(
                        qf[g][ks], kf[ks][sub], sc[g][sub], 0, 0, 0);

        // ---- online softmax (exp2 domain) ----
#pragma unroll
        for (int g = 0; g < 2; ++g) {
            float mx[4];
#pragma unroll
            for (int r = 0; r < 4; ++r)
                mx[r] = fmaxf(fmaxf(sc[g][0][r], sc[g][1][r]), fmaxf(sc[g][2][r], sc[g][3][r]));
#pragma unroll
            for (int off = 1; off < 16; off <<= 1)
#pragma unroll
                for (int r = 0; r < 4; ++r)
                    mx[r] = fmaxf(mx[r], __shfl_xor(mx[r], off, 64));

            float al[4];
#pragma unroll
            for (int r = 0; r < 4; ++r) {
                float mn = fmaxf(m_i[g][r], mx[r]);
                al[r] = exp2f(m_i[g][r] - mn);
                m_i[g][r] = mn;
            }
#pragma unroll
            for (int sub = 0; sub < 4; ++sub)
#pragma unroll
                for (int r = 0; r < 4; ++r) {
                    float p = exp2f(sc[g][sub][r] - m_i[g][r]);
                    unsigned int wbits = (sub < 2) ? wlo[g][r] : whi[g][r];
                    p = ((wbits >> ((sub & 1) * 16 + l15)) & 1u) ? p : 0.0f;
                    sc[g][sub][r] = p;
                }
            float rs[4];
#pragma unroll
            for (int r = 0; r < 4; ++r)
                rs[r] = (sc[g][0][r] + sc[g][1][r]) + (sc[g][2][r] + sc[g][3][r]);
#pragma unroll
            for (int off = 1; off < 16; off <<= 1)
#pragma unroll
                for (int r = 0; r < 4; ++r)
                    rs[r] += __shfl_xor(rs[r], off, 64);
#pragma unroll
            for (int r = 0; r < 4; ++r) l_i[g][r] = l_i[g][r] * al[r] + rs[r];
#pragma unroll
            for (int hs = 0; hs < 4; ++hs)
#pragma unroll
                for (int r = 0; r < 4; ++r) acc[g][hs][r] *= al[r];
            // P -> LDS (C-layout scatter, bf16)
#pragma unroll
            for (int sub = 0; sub < 4; ++sub)
#pragma unroll
                for (int r = 0; r < 4; ++r)
                    Ps[w][g * 16 + quad * 4 + r][sub * 16 + l15] = f2bf(sc[g][sub][r]);
        }

        __syncthreads();   // cheap; guarantees P write->read ordering

        // ---- PV ----
        short8 pf[2][2];
#pragma unroll
        for (int g = 0; g < 2; ++g)
#pragma unroll
            for (int ks = 0; ks < 2; ++ks)
                pf[g][ks] = *(const short8*)&Ps[w][g * 16 + l15][ks * 32 + quad * 8];
#pragma unroll
        for (int ks = 0; ks < 2; ++ks)
#pragma unroll
            for (int hs = 0; hs < 4; ++hs)
#pragma unroll
                for (int g = 0; g < 2; ++g)
                    acc[g][hs] = __builtin_amdgcn_mfma_f32_16x16x32_bf16(
                        pf[g][ks], vf[hs][ks], acc[g][hs], 0, 0, 0);
        __syncthreads();   // protect Ps against next-iter overwrite skew
    }

    // epilogue: ctx fp32 [B, S, D]
#pragma unroll
    for (int g = 0; g < 2; ++g) {
        float inv[4];
#pragma unroll
        for (int r = 0; r < 4; ++r) inv[r] = 1.0f / fmaxf(l_i[g][r], 1e-30f);
#pragma unroll
        for (int hs = 0; hs < 4; ++hs)
#pragma unroll
            for (int r = 0; r < 4; ++r) {
                int row = qrow0 + g * 16 + quad * 4 + r;
                int col = h * 64 + hs * 16 + l15;
                ctx[(size_t)(b * Sdim + row) * Ddim + col] = acc[g][hs][r] * inv[r];
            }
    }
}

// ---------------------------------------------------------------------------
// Output projection (fp32): out = ctx @ Wo + bo.
// ---------------------------------------------------------------------------
__global__ __launch_bounds__(256) void out_gemm_kernel(
    const float* __restrict__ A, const float* __restrict__ W,
    const float* __restrict__ bias, float* __restrict__ out)
{
    __shared__ float As[128][20];
    __shared__ float Bs[16][132];

    const int t  = threadIdx.x;
    const int tx = t & 15;
    const int ty = t >> 4;
    const int n0 = blockIdx.x * 128;
    const int m0 = blockIdx.y * 128;

    const int ar0 = t >> 2;
    const int ac  = (t & 3) * 4;
    const int br0 = t >> 5;
    const int bc  = (t & 31) * 4;

    float acc[8][8];
#pragma unroll
    for (int i = 0; i < 8; ++i)
#pragma unroll
        for (int j = 0; j < 8; ++j) acc[i][j] = 0.f;

    for (int kt = 0; kt < 64; ++kt) {
        const int k0 = kt * 16;
        float4 av0 = *(const float4*)(A + (size_t)(m0 + ar0) * Ddim + k0 + ac);
        float4 av1 = *(const float4*)(A + (size_t)(m0 + ar0 + 64) * Ddim + k0 + ac);
        float4 bw0 = *(const float4*)(W + (size_t)(k0 + br0) * Ddim + n0 + bc);
        float4 bw1 = *(const float4*)(W + (size_t)(k0 + br0 + 8) * Ddim + n0 + bc);
        __syncthreads();
        *(float4*)&As[ar0][ac]      = av0;
        *(float4*)&As[ar0 + 64][ac] = av1;
        *(float4*)&Bs[br0][bc]      = bw0;
        *(float4*)&Bs[br0 + 8][bc]  = bw1;
        __syncthreads();
#pragma unroll
        for (int k4 = 0; k4 < 4; ++k4) {
            float4 a4[8];
#pragma unroll
            for (int i = 0; i < 8; ++i)
                a4[i] = *(const float4*)&As[i * 16 + ty][k4 * 4];
#pragma unroll
            for (int kk = 0; kk < 4; ++kk) {
                float4 b0 = *(const float4*)&Bs[k4 * 4 + kk][tx * 8];
                float4 b1 = *(const float4*)&Bs[k4 * 4 + kk][tx * 8 + 4];
#pragma unroll
                for (int i = 0; i < 8; ++i) {
                    float av = ((const float*)&a4[i])[kk];
                    acc[i][0] += av * b0.x; acc[i][1] += av * b0.y;
                    acc[i][2] += av * b0.z; acc[i][3] += av * b0.w;
                    acc[i][4] += av * b1.x; acc[i][5] += av * b1.y;
                    acc[i][6] += av * b1.z; acc[i][7] += av * b1.w;
                }
            }
        }
    }

    float bvv[8];
#pragma unroll
    for (int j = 0; j < 8; ++j) bvv[j] = bias[n0 + tx * 8 + j];
#pragma unroll
    for (int i = 0; i < 8; ++i) {
        int m = m0 + i * 16 + ty;
        float* dst = out + (size_t)m * Ddim + n0 + tx * 8;
        *(float4*)dst       = make_float4(acc[i][0] + bvv[0], acc[i][1] + bvv[1],
                                          acc[i][2] + bvv[2], acc[i][3] + bvv[3]);
        *(float4*)(dst + 4) = make_float4(acc[i][4] + bvv[4], acc[i][5] + bvv[5],
                                          acc[i][6] + bvv[6], acc[i][7] + bvv[7]);
    }
}

// ---------------------------------------------------------------------------
extern "C" void kernel_launch(void* const* d_in, const int* in_sizes, int n_in,
                              void* d_out, int out_size, void* d_ws, size_t ws_size,
                              hipStream_t stream) {
    const float* x   = (const float*)d_in[0];
    const float* Wq  = (const float*)d_in[1];
    const float* bq  = (const float*)d_in[2];
    const float* Wk  = (const float*)d_in[3];
    const float* bk  = (const float*)d_in[4];
    const float* Wv  = (const float*)d_in[5];
    const float* bv  = (const float*)d_in[6];
    const float* Wo  = (const float*)d_in[7];
    const float* bo  = (const float*)d_in[8];
    // d_in[9] cross_modal_weights: bias is softmax-shift-invariant -> unused
    const int*  mask = (const int*)d_in[10];
    // d_in[11] modality_info: unused by the reference
    float* out = (float*)d_out;

    char* ws = (char*)d_ws;
    unsigned short* qb  = (unsigned short*)(ws);                         // 8 MB
    unsigned short* kb  = (unsigned short*)(ws + (size_t)8  * 1048576);  // 8 MB
    unsigned short* vb  = (unsigned short*)(ws + (size_t)16 * 1048576);  // 8 MB
    unsigned short* vtb = (unsigned short*)(ws + (size_t)24 * 1048576);  // 8 MB
    unsigned int*   pmk = (unsigned int*)  (ws + (size_t)32 * 1048576);  // 1 MB
    float*          ctx = (float*)         (ws + (size_t)40 * 1048576);  // 16 MB

    qkv_gemm_kernel<<<dim3(24, 32), 256, 0, stream>>>(x, Wq, Wk, Wv, bq, bk, bv,
                                                      qb, kb, vb);
    pack_mask_kernel<<<dim3(32768), 256, 0, stream>>>(mask, (unsigned long long*)pmk);
    transpose_v_kernel<<<dim3(32, 32), 256, 0, stream>>>(vb, vtb);
    attn_mfma_kernel<<<dim3(16, 32), 256, 0, stream>>>(qb, kb, vtb, pmk, ctx);
    out_gemm_kernel<<<dim3(8, 32), 256, 0, stream>>>(ctx, Wo, bo, out);
}

// Round 3
// 360.518 us; speedup vs baseline: 5.4500x; 1.9337x over previous
//
#include <hip/hip_runtime.h>
#include <math.h>

#define Bdim 2
#define Sdim 2048
#define Ddim 1024
#define Hnum 16
#define HDdim 64
#define Kdim 1024

using short8  = __attribute__((ext_vector_type(8))) short;
using ushort8 = __attribute__((ext_vector_type(8))) unsigned short;
using floatx4 = __attribute__((ext_vector_type(4))) float;

__device__ __forceinline__ unsigned short f2bf(float f) {
    __bf16 b = (__bf16)f;
    return __builtin_bit_cast(unsigned short, b);
}

// async global->LDS, 16B per lane. LDS dest is wave-uniform base + lane*16,
// so callers must pass lane-contiguous lds addresses (flat*16).
__device__ __forceinline__ void async_ld16(const unsigned short* g, unsigned short* l) {
    __builtin_amdgcn_global_load_lds(
        (const __attribute__((address_space(1))) unsigned int*)(g),
        (__attribute__((address_space(3))) unsigned int*)(l), 16, 0, 0);
}

// ---------------------------------------------------------------------------
// x fp32 -> bf16 (same layout).
// ---------------------------------------------------------------------------
__global__ __launch_bounds__(256) void convert_x_kernel(
    const float* __restrict__ x, unsigned short* __restrict__ xb)
{
    size_t i = ((size_t)blockIdx.x * 256 + threadIdx.x) * 8;
    float4 a = *(const float4*)(x + i);
    float4 b = *(const float4*)(x + i + 4);
    ushort8 o;
    o[0] = f2bf(a.x); o[1] = f2bf(a.y); o[2] = f2bf(a.z); o[3] = f2bf(a.w);
    o[4] = f2bf(b.x); o[5] = f2bf(b.y); o[6] = f2bf(b.z); o[7] = f2bf(b.w);
    *(ushort8*)(xb + i) = o;
}

// ---------------------------------------------------------------------------
// W [k][n] fp32 -> Wt [mat][n][k] bf16 (transpose), 64x64 tiles via LDS.
// ---------------------------------------------------------------------------
__global__ __launch_bounds__(256) void transpose_w_kernel(
    const float* __restrict__ Wq, const float* __restrict__ Wk,
    const float* __restrict__ Wv, const float* __restrict__ Wo,
    unsigned short* __restrict__ Wt)
{
    __shared__ float tile[64][65];
    const int z = blockIdx.z;
    const float* W = (z == 0) ? Wq : (z == 1) ? Wk : (z == 2) ? Wv : Wo;
    unsigned short* outp = Wt + (size_t)z * Kdim * Ddim;
    const int n0 = blockIdx.x * 64;
    const int k0 = blockIdx.y * 64;
    const int t = threadIdx.x;
#pragma unroll
    for (int i = 0; i < 4; ++i) {
        int flat = i * 256 + t;
        int r = flat >> 4;
        int c = (flat & 15) * 4;
        float4 v = *(const float4*)(W + (size_t)(k0 + r) * Ddim + n0 + c);
        tile[r][c] = v.x; tile[r][c + 1] = v.y; tile[r][c + 2] = v.z; tile[r][c + 3] = v.w;
    }
    __syncthreads();
#pragma unroll
    for (int i = 0; i < 16; ++i) {
        int flat = i * 256 + t;
        int n = flat >> 6;
        int k = flat & 63;
        outp[(size_t)(n0 + n) * Kdim + k0 + k] = f2bf(tile[k][n]);
    }
}

// ---------------------------------------------------------------------------
// Pack mask int32 [B,S,S] -> bitmask uint64 [B,S,S/64] via ballot.
// ---------------------------------------------------------------------------
__global__ __launch_bounds__(256) void pack_mask_kernel(
    const int* __restrict__ mask, unsigned long long* __restrict__ packed)
{
    const int t = threadIdx.x;
    const size_t widx = (size_t)blockIdx.x * 4 + (t >> 6);
    const int lane = t & 63;
    int mv = mask[widx * 64 + lane];
    unsigned long long bits = __ballot(mv != 0);
    if (lane == 0) packed[widx] = bits;
}

// ---------------------------------------------------------------------------
// Transpose V: bf16 [bh][s][hd] -> bf16 [bh][hd][s].
// ---------------------------------------------------------------------------
__global__ __launch_bounds__(256) void transpose_v_kernel(
    const unsigned short* __restrict__ v, unsigned short* __restrict__ vt)
{
    const int t  = threadIdx.x;
    const int s0 = blockIdx.x * 64;
    const int bh = blockIdx.y;
    const unsigned short* vp = v + (size_t)bh * Sdim * HDdim;
    unsigned short* vtp      = vt + (size_t)bh * HDdim * Sdim;
    const int c  = t & 63;
    const int rg = t >> 6;
#pragma unroll
    for (int half = 0; half < 2; ++half) {
        int r0 = (rg + half * 4) * 8;
        ushort8 o;
#pragma unroll
        for (int j = 0; j < 8; ++j) o[j] = vp[(size_t)(s0 + r0 + j) * HDdim + c];
        *(ushort8*)(vtp + (size_t)c * Sdim + s0 + r0) = o;
    }
}

// ---------------------------------------------------------------------------
// bf16 MFMA GEMM core (m97 structure): C = A[m][k] . Wt[n][k]^T
// 128x128 block, BK=64, 4 waves (2x2), each wave 4x4 16x16x32 MFMAs.
// XOR k-chunk swizzle applied at the *global source* so lane-contiguous
// global_load_lds staging lands swizzled; ds_read_b128 then <=2-way banked.
// ---------------------------------------------------------------------------
#define GEMM_CORE(APTR, WPTR)                                                    \
    __shared__ __align__(16) unsigned short As[128 * 64];                        \
    __shared__ __align__(16) unsigned short Bs[128 * 64];                        \
    const int t    = threadIdx.x;                                                \
    const int lane = t & 63;                                                     \
    const int w    = t >> 6;                                                     \
    const int quad = lane >> 4;                                                  \
    const int l15  = lane & 15;                                                  \
    const int wm   = w & 1;                                                      \
    const int wn   = w >> 1;                                                     \
    floatx4 acc[4][4];                                                           \
    _Pragma("unroll")                                                            \
    for (int mt = 0; mt < 4; ++mt)                                               \
        _Pragma("unroll")                                                        \
        for (int nt = 0; nt < 4; ++nt) acc[mt][nt] = (floatx4){0.f,0.f,0.f,0.f}; \
    for (int kt = 0; kt < 16; ++kt) {                                            \
        const int k0 = kt * 64;                                                  \
        __syncthreads();                                                         \
        _Pragma("unroll")                                                        \
        for (int i = 0; i < 4; ++i) {                                            \
            int flat = i * 256 + t;                                              \
            int row  = flat >> 3;                                                \
            int cg   = (flat & 7) ^ (row & 7);                                   \
            async_ld16(APTR + (size_t)(m0 + row) * Kdim + k0 + cg * 8,           \
                       As + flat * 8);                                           \
        }                                                                        \
        _Pragma("unroll")                                                        \
        for (int i = 0; i < 4; ++i) {                                            \
            int flat = i * 256 + t;                                              \
            int row  = flat >> 3;                                                \
            int cg   = (flat & 7) ^ (row & 7);                                   \
            async_ld16(WPTR + (size_t)row * Kdim + k0 + cg * 8,                  \
                       Bs + flat * 8);                                           \
        }                                                                        \
        __syncthreads();                                                         \
        _Pragma("unroll")                                                        \
        for (int ks = 0; ks < 2; ++ks) {                                         \
            short8 af[4], bfr[4];                                                \
            _Pragma("unroll")                                                    \
            for (int mt = 0; mt < 4; ++mt) {                                     \
                int row = wm * 64 + mt * 16 + l15;                               \
                int ch  = (ks * 4 + quad) ^ (row & 7);                           \
                af[mt] = *(const short8*)(As + row * 64 + ch * 8);               \
            }                                                                    \
            _Pragma("unroll")                                                    \
            for (int nt = 0; nt < 4; ++nt) {                                     \
                int row = wn * 64 + nt * 16 + l15;                               \
                int ch  = (ks * 4 + quad) ^ (row & 7);                           \
                bfr[nt] = *(const short8*)(Bs + row * 64 + ch * 8);              \
            }                                                                    \
            _Pragma("unroll")                                                    \
            for (int mt = 0; mt < 4; ++mt)                                       \
                _Pragma("unroll")                                                \
                for (int nt = 0; nt < 4; ++nt)                                   \
                    acc[mt][nt] = __builtin_amdgcn_mfma_f32_16x16x32_bf16(       \
                        af[mt], bfr[nt], acc[mt][nt], 0, 0, 0);                  \
        }                                                                        \
    }

// QKV: A = xb [4096][1024], Wt = [3][n][k]; writes bf16 q/k/v in [bh][s][hd].
__global__ __launch_bounds__(256) void qkv_mfma_kernel(
    const unsigned short* __restrict__ A, const unsigned short* __restrict__ Wt,
    const float* __restrict__ bq, const float* __restrict__ bk, const float* __restrict__ bv,
    unsigned short* __restrict__ qo, unsigned short* __restrict__ ko, unsigned short* __restrict__ vo)
{
    const int n0   = blockIdx.x * 128;
    const int m0   = blockIdx.y * 128;
    const int wsel = n0 >> 10;
    const int c0   = n0 & 1023;
    const unsigned short* Wp = Wt + (size_t)wsel * Kdim * Ddim + (size_t)c0 * Kdim;

    GEMM_CORE(A, Wp)

    const float* bias = (wsel == 0) ? bq : (wsel == 1) ? bk : bv;
    unsigned short* outp = (wsel == 0) ? qo : (wsel == 1) ? ko : vo;
    const float qsc = (wsel == 0) ? 0.18033688011112042f : 1.0f;  // 0.125*log2(e)
#pragma unroll
    for (int nt = 0; nt < 4; ++nt) {
        int c = c0 + wn * 64 + nt * 16 + l15;
        float bb = bias[c];
        int h  = c >> 6;
        int hd = c & 63;
#pragma unroll
        for (int mt = 0; mt < 4; ++mt) {
#pragma unroll
            for (int r = 0; r < 4; ++r) {
                int m    = m0 + wm * 64 + mt * 16 + quad * 4 + r;
                int bidx = m >> 11;
                int s    = m & 2047;
                outp[((size_t)(bidx * Hnum + h) * Sdim + s) * HDdim + hd] =
                    f2bf((acc[mt][nt][r] + bb) * qsc);
            }
        }
    }
}

// Out: A = ctx bf16 [4096][1024], W = Wt[3] (Wo); writes fp32 out + bias.
__global__ __launch_bounds__(256) void out_mfma_kernel(
    const unsigned short* __restrict__ A, const unsigned short* __restrict__ Wt,
    const float* __restrict__ bias, float* __restrict__ out)
{
    const int n0 = blockIdx.x * 128;
    const int m0 = blockIdx.y * 128;
    const unsigned short* Wp = Wt + (size_t)3 * Kdim * Ddim + (size_t)n0 * Kdim;

    GEMM_CORE(A, Wp)

#pragma unroll
    for (int nt = 0; nt < 4; ++nt) {
        int c = n0 + wn * 64 + nt * 16 + l15;
        float bb = bias[c];
#pragma unroll
        for (int mt = 0; mt < 4; ++mt) {
#pragma unroll
            for (int r = 0; r < 4; ++r) {
                int m = m0 + wm * 64 + mt * 16 + quad * 4 + r;
                out[(size_t)m * Ddim + c] = acc[mt][nt][r] + bb;
            }
        }
    }
}

// ---------------------------------------------------------------------------
// MFMA flash attention (round-2 kernel; epilogue now writes bf16 ctx).
// ---------------------------------------------------------------------------
__global__ __launch_bounds__(256, 2) void attn_mfma_kernel(
    const unsigned short* __restrict__ q, const unsigned short* __restrict__ k,
    const unsigned short* __restrict__ vt, const unsigned int* __restrict__ pmask,
    unsigned short* __restrict__ ctx)
{
    __shared__ unsigned short Ps[4][32][72];

    const int t    = threadIdx.x;
    const int w    = t >> 6;
    const int lane = t & 63;
    const int quad = lane >> 4;
    const int l15  = lane & 15;
    const int bh   = blockIdx.y;
    const int b    = bh >> 4;
    const int h    = bh & 15;
    const int qrow0 = blockIdx.x * 128 + w * 32;

    const unsigned short* qp = q  + (size_t)bh * Sdim * HDdim;
    const unsigned short* kp = k  + (size_t)bh * Sdim * HDdim;
    const unsigned short* vp = vt + (size_t)bh * HDdim * Sdim;

    short8 qf[2][2];
#pragma unroll
    for (int g = 0; g < 2; ++g)
#pragma unroll
        for (int ks = 0; ks < 2; ++ks)
            qf[g][ks] = *(const short8*)(qp + (size_t)(qrow0 + g * 16 + l15) * HDdim + ks * 32 + quad * 8);

    floatx4 acc[2][4];
    float m_i[2][4], l_i[2][4];
#pragma unroll
    for (int g = 0; g < 2; ++g) {
#pragma unroll
        for (int hs = 0; hs < 4; ++hs) acc[g][hs] = (floatx4){0.f, 0.f, 0.f, 0.f};
#pragma unroll
        for (int r = 0; r < 4; ++r) { m_i[g][r] = -__builtin_inff(); l_i[g][r] = 0.f; }
    }

    for (int kt = 0; kt < 32; ++kt) {
        const int key0 = kt * 64;

        short8 kf[2][4];
#pragma unroll
        for (int ks = 0; ks < 2; ++ks)
#pragma unroll
            for (int sub = 0; sub < 4; ++sub)
                kf[ks][sub] = *(const short8*)(kp + (size_t)(key0 + sub * 16 + l15) * HDdim + ks * 32 + quad * 8);

        short8 vf[4][2];
#pragma unroll
        for (int hs = 0; hs < 4; ++hs)
#pragma unroll
            for (int ks = 0; ks < 2; ++ks)
                vf[hs][ks] = *(const short8*)(vp + (size_t)(hs * 16 + l15) * Sdim + key0 + ks * 32 + quad * 8);

        unsigned int wlo[2][4], whi[2][4];
#pragma unroll
        for (int g = 0; g < 2; ++g)
#pragma unroll
            for (int r = 0; r < 4; ++r) {
                size_t mi = ((size_t)(b * Sdim + qrow0 + g * 16 + quad * 4 + r) * 32 + kt) * 2;
                wlo[g][r] = pmask[mi];
                whi[g][r] = pmask[mi + 1];
            }

        floatx4 sc[2][4];
#pragma unroll
        for (int g = 0; g < 2; ++g)
#pragma unroll
            for (int sub = 0; sub < 4; ++sub) sc[g][sub] = (floatx4){0.f, 0.f, 0.f, 0.f};
#pragma unroll
        for (int ks = 0; ks < 2; ++ks)
#pragma unroll
            for (int sub = 0; sub < 4; ++sub)
#pragma unroll
                for (int g = 0; g < 2; ++g)
                    sc[g][sub] = __builtin_amdgcn_mfma_f32_16x16x32_bf16(
                        qf[g][ks], kf[ks][sub], sc[g][sub], 0, 0, 0);

#pragma unroll
        for (int g = 0; g < 2; ++g) {
            float mx[4];
#pragma unroll
            for (int r = 0; r < 4; ++r)
                mx[r] = fmaxf(fmaxf(sc[g][0][r], sc[g][1][r]), fmaxf(sc[g][2][r], sc[g][3][r]));
#pragma unroll
            for (int off = 1; off < 16; off <<= 1)
#pragma unroll
                for (int r = 0; r < 4; ++r)
                    mx[r] = fmaxf(mx[r], __shfl_xor(mx[r], off, 64));

            float al[4];
#pragma unroll
            for (int r = 0; r < 4; ++r) {
                float mn = fmaxf(m_i[g][r], mx[r]);
                al[r] = exp2f(m_i[g][r] - mn);
                m_i[g][r] = mn;
            }
#pragma unroll
            for (int sub = 0; sub < 4; ++sub)
#pragma unroll
                for (int r = 0; r < 4; ++r) {
                    float p = exp2f(sc[g][sub][r] - m_i[g][r]);
                    unsigned int wbits = (sub < 2) ? wlo[g][r] : whi[g][r];
                    p = ((wbits >> ((sub & 1) * 16 + l15)) & 1u) ? p : 0.0f;
                    sc[g][sub][r] = p;
                }
            float rs[4];
#pragma unroll
            for (int r = 0; r < 4; ++r)
                rs[r] = (sc[g][0][r] + sc[g][1][r]) + (sc[g][2][r] + sc[g][3][r]);
#pragma unroll
            for (int off = 1; off < 16; off <<= 1)
#pragma unroll
                for (int r = 0; r < 4; ++r)
                    rs[r] += __shfl_xor(rs[r], off, 64);
#pragma unroll
            for (int r = 0; r < 4; ++r) l_i[g][r] = l_i[g][r] * al[r] + rs[r];
#pragma unroll
            for (int hs = 0; hs < 4; ++hs)
#pragma unroll
                for (int r = 0; r < 4; ++r) acc[g][hs][r] *= al[r];
#pragma unroll
            for (int sub = 0; sub < 4; ++sub)
#pragma unroll
                for (int r = 0; r < 4; ++r)
                    Ps[w][g * 16 + quad * 4 + r][sub * 16 + l15] = f2bf(sc[g][sub][r]);
        }

        __syncthreads();

        short8 pf[2][2];
#pragma unroll
        for (int g = 0; g < 2; ++g)
#pragma unroll
            for (int ks = 0; ks < 2; ++ks)
                pf[g][ks] = *(const short8*)&Ps[w][g * 16 + l15][ks * 32 + quad * 8];
#pragma unroll
        for (int ks = 0; ks < 2; ++ks)
#pragma unroll
            for (int hs = 0; hs < 4; ++hs)
#pragma unroll
                for (int g = 0; g < 2; ++g)
                    acc[g][hs] = __builtin_amdgcn_mfma_f32_16x16x32_bf16(
                        pf[g][ks], vf[hs][ks], acc[g][hs], 0, 0, 0);
        __syncthreads();
    }

#pragma unroll
    for (int g = 0; g < 2; ++g) {
        float inv[4];
#pragma unroll
        for (int r = 0; r < 4; ++r) inv[r] = 1.0f / fmaxf(l_i[g][r], 1e-30f);
#pragma unroll
        for (int hs = 0; hs < 4; ++hs)
#pragma unroll
            for (int r = 0; r < 4; ++r) {
                int row = qrow0 + g * 16 + quad * 4 + r;
                int col = h * 64 + hs * 16 + l15;
                ctx[(size_t)(b * Sdim + row) * Ddim + col] = f2bf(acc[g][hs][r] * inv[r]);
            }
    }
}

// ---------------------------------------------------------------------------
extern "C" void kernel_launch(void* const* d_in, const int* in_sizes, int n_in,
                              void* d_out, int out_size, void* d_ws, size_t ws_size,
                              hipStream_t stream) {
    const float* x   = (const float*)d_in[0];
    const float* Wq  = (const float*)d_in[1];
    const float* bq  = (const float*)d_in[2];
    const float* Wk  = (const float*)d_in[3];
    const float* bk  = (const float*)d_in[4];
    const float* Wv  = (const float*)d_in[5];
    const float* bv  = (const float*)d_in[6];
    const float* Wo  = (const float*)d_in[7];
    const float* bo  = (const float*)d_in[8];
    // d_in[9] cross_modal_weights: softmax-shift-invariant -> unused
    const int*  mask = (const int*)d_in[10];
    // d_in[11] modality_info: unused by the reference
    float* out = (float*)d_out;

    char* ws = (char*)d_ws;
    unsigned short* xb  = (unsigned short*)(ws);                         // 8 MB
    unsigned short* Wt  = (unsigned short*)(ws + (size_t)8  * 1048576);  // 8 MB (4x [n][k] bf16)
    unsigned short* qb  = (unsigned short*)(ws + (size_t)16 * 1048576);  // 8 MB
    unsigned short* kb  = (unsigned short*)(ws + (size_t)24 * 1048576);  // 8 MB
    unsigned short* vb  = (unsigned short*)(ws + (size_t)32 * 1048576);  // 8 MB
    unsigned short* vtb = (unsigned short*)(ws + (size_t)40 * 1048576);  // 8 MB
    unsigned int*   pmk = (unsigned int*)  (ws + (size_t)48 * 1048576);  // 1 MB
    unsigned short* ctxb = xb;  // alias: xb consumed before attn writes ctx

    convert_x_kernel<<<dim3(2048), 256, 0, stream>>>(x, xb);
    transpose_w_kernel<<<dim3(16, 16, 4), 256, 0, stream>>>(Wq, Wk, Wv, Wo, Wt);
    pack_mask_kernel<<<dim3(32768), 256, 0, stream>>>(mask, (unsigned long long*)pmk);
    qkv_mfma_kernel<<<dim3(24, 32), 256, 0, stream>>>(xb, Wt, bq, bk, bv, qb, kb, vb);
    transpose_v_kernel<<<dim3(32, 32), 256, 0, stream>>>(vb, vtb);
    attn_mfma_kernel<<<dim3(16, 32), 256, 0, stream>>>(qb, kb, vtb, pmk, ctxb);
    out_mfma_kernel<<<dim3(8, 32), 256, 0, stream>>>(ctxb, Wt, bo, out);
}